// Round 11
// baseline (405.692 us; speedup 1.0000x reference)
//
#include <hip/hip_runtime.h>

// VQ layer B=16,D=64,T=8192,E=512 — f16 MFMA prefilter + exact numpy-fp32 windowed refine.
// Frozen exact recipe (r2..r10, absmax 0): s1=pairwise-8; G=seq-k FMA; c2=seq outer;
// key=(s1-2G)+c2 left-assoc; first-index strict-min.
// Round 11: COMPACT the ambiguous queries (atomicAdd + ballot rank) instead of sparse
// per-wave ballots; rescan kernel grid-strides the dense list with one wave per query
// (r10's B: 4096 mostly-idle blocks, serial entries, 13% occupancy, 72us).
// ws layout: [0,65536)B f16 frags; [65536,67584)B c2 float[512]; [67584]B u32 counter;
//            [67600,133136)B int list[16384].

constexpr int Dc = 64, Ec = 512, Tc = 8192;
constexpr int QTOT = 131072, ZQ = 8388608;
constexpr int QPB = 256;          // 8 waves x 32 queries
constexpr int NBLK = QTOT / QPB;  // 512
constexpr int CAP = 16384;        // list capacity (measured amb rate ~4.3% -> ~5600)

using half8  = __attribute__((ext_vector_type(8))) _Float16;
using f32x16 = __attribute__((ext_vector_type(16))) float;

__device__ __forceinline__ unsigned* ws_counter(_Float16* wsf) {
    return (unsigned*)((char*)wsf + 67584);
}
__device__ __forceinline__ int* ws_list(_Float16* wsf) {
    return (int*)((char*)wsf + 67600);
}

// prep: (a) 64 slots x 1KB f16 frags (r9-validated layout, c scaled x512),
//       (b) c2 numpy-exact (seq outer-axis), (c) zero the compaction counter.
__global__ void vq_prep(const float* __restrict__ cbfull, const int* __restrict__ cbidx,
                        _Float16* __restrict__ wsf) {
    int tid = blockIdx.x * 256 + threadIdx.x;
    if (tid == 0) *ws_counter(wsf) = 0;
    const float* cb = cbfull + (size_t)(cbidx[0] & 3) * (Dc * Ec);
    if (tid < 512) {
        float c = cb[tid];
        float a = __fmul_rn(c, c);
        for (int d = 1; d < Dc; ++d) { c = cb[d * Ec + tid]; a = __fadd_rn(a, __fmul_rn(c, c)); }
        ((float*)(wsf + 32768))[tid] = a;
    }
    if (tid >= 4096) return;
    int l = tid & 63, c = (tid >> 6) & 3, g = tid >> 8;
    int n = g * 32 + (l & 31);
    int kbase = c * 16 + (l >> 5) * 8;
    _Float16* dst = wsf + (size_t)(g * 4 + c) * 512 + l * 8;
    #pragma unroll
    for (int i = 0; i < 8; ++i)
        dst[i] = (_Float16)(cb[(kbase + i) * Ec + n] * 512.0f);
}

__global__ __launch_bounds__(512) void vq_main(
    const float* __restrict__ z, const float* __restrict__ cbfull,
    const int* __restrict__ cbidx, _Float16* __restrict__ wsf,
    float* __restrict__ out) {
    __shared__ __attribute__((aligned(16))) _Float16 s_frag[32768];  // 64KB
    __shared__ float s_c2[Ec];
    __shared__ unsigned s_w[QPB];
    __shared__ int s_idx[QPB];

    const int tid = threadIdx.x;
    const int lane = tid & 63;
    const int wave = __builtin_amdgcn_readfirstlane(tid >> 6);  // 0..7 (SGPR)
    const int col = lane & 31, hh = lane >> 5;
    const int q0 = blockIdx.x * QPB;
    const int b = q0 >> 13, t0 = q0 & (Tc - 1);
    const int myq = wave * 32 + col;
    const int t = t0 + myq;

    const int ci = cbidx[0] & 3;
    const float* __restrict__ cb = cbfull + (size_t)ci * (Dc * Ec);

    // query vector -> registers FIRST (HBM latency overlaps staging below)
    float zv[32];
    const float* zp = z + (size_t)b * Dc * Tc + t;
    #pragma unroll
    for (int c = 0; c < 4; ++c)
        #pragma unroll
        for (int i = 0; i < 8; ++i)
            zv[c * 8 + i] = zp[(size_t)(c * 16 + hh * 8 + i) * Tc];

    // one-shot stage: 64KB frags, 8 uint4/thread, coalesced, static indices
    {
        const uint4* src = (const uint4*)wsf;
        uint4* dst = (uint4*)s_frag;
        #pragma unroll
        for (int k = 0; k < 8; ++k) dst[tid + k * 512] = src[tid + k * 512];
    }
    if (tid < 512) s_c2[tid] = ((const float*)(wsf + 32768))[tid];

    // ambiguity window (r9-validated constants)
    float s1p = 0.f;
    #pragma unroll
    for (int e = 0; e < 32; ++e) s1p = __fmaf_rn(zv[e], zv[e], s1p);
    float s1b = (s1p + __shfl_xor(s1p, 32, 64)) * 1.001f + 0.01f;
    float wf = 2.5e-7f * (s1b + 1.f) + 3.2e-5f * sqrtf(s1b) + 1e-5f;
    unsigned w_int = (s1b > 880.f) ? 0x7FFFFFFFu : (unsigned)(wf * 2.147483648e9f) + 512u;
    if (hh == 0) s_w[myq] = w_int;

    // A-frags: u' = -16*z, f16 hi + lo
    half8 uhf[4], ulf[4];
    #pragma unroll
    for (int c = 0; c < 4; ++c)
        #pragma unroll
        for (int i = 0; i < 8; ++i) {
            float f = -16.0f * zv[c * 8 + i];
            _Float16 h = (_Float16)f;
            float hf = (float)h;
            uhf[c][i] = h;
            ulf[c][i] = (_Float16)(f - hf);
        }

    __syncthreads();   // frags + c2 + s_w ready

    // GEMM: 16 groups x {4 ds_read_b128, 8 MFMA f16, pack+min1/min2}; waves independent.
    // kb pre-biased: acc = 4096*(c2 - 2*z.c + 3) in [2^13,2^14) (s1<=880 guard).
    unsigned m1[16], m2[16];
    #pragma unroll
    for (int r = 0; r < 16; ++r) { m1[r] = 0xFFFFFFFFu; m2[r] = 0xFFFFFFFFu; }

    #pragma unroll 2
    for (int g = 0; g < 16; ++g) {
        const float kb = __fmaf_rn(s_c2[g * 32 + col], 4096.0f, 12288.0f);
        f32x16 acc;
        #pragma unroll
        for (int r = 0; r < 16; ++r) acc[r] = kb;
        #pragma unroll
        for (int c = 0; c < 4; ++c) {
            half8 chf = *(const half8*)(s_frag + (size_t)(g * 4 + c) * 512 + lane * 8);
            acc = __builtin_amdgcn_mfma_f32_32x32x16_f16(uhf[c], chf, acc, 0, 0, 0);
            acc = __builtin_amdgcn_mfma_f32_32x32x16_f16(ulf[c], chf, acc, 0, 0, 0);
        }
        const unsigned jj = (unsigned)(g * 32 + col);
        #pragma unroll
        for (int r = 0; r < 16; ++r) {
            unsigned key = (__float_as_uint(acc[r]) << 9) | jj;   // exp fixed -> monotone
            unsigned mx = key > m1[r] ? key : m1[r];
            m1[r] = key < m1[r] ? key : m1[r];
            m2[r] = mx < m2[r] ? mx : m2[r];
        }
    }

    // min1/min2 butterfly across 32 code-cols (register-only)
    #pragma unroll
    for (int st = 1; st < 32; st <<= 1) {
        #pragma unroll
        for (int r = 0; r < 16; ++r) {
            unsigned o1 = __shfl_xor(m1[r], st, 64);
            unsigned o2 = __shfl_xor(m2[r], st, 64);
            unsigned mx = m1[r] > o1 ? m1[r] : o1;
            m1[r] = m1[r] < o1 ? m1[r] : o1;
            m2[r] = m2[r] < o2 ? m2[r] : o2;
            m2[r] = m2[r] < mx ? m2[r] : mx;
        }
    }

    // lane col<16 owns accumulator r=col
    unsigned F1 = 0xFFFFFFFFu, F2 = 0xFFFFFFFFu;
    #pragma unroll
    for (int r = 0; r < 16; ++r) if (col == r) { F1 = m1[r]; F2 = m2[r]; }
    bool amb = false;
    int Q = 0;
    if (col < 16) {
        int row = (col & 3) + 8 * (col >> 2) + 4 * hh;   // verified 32x32 C/D row map
        Q = wave * 32 + row;
        s_idx[Q] = (int)(F1 & 511u);
        unsigned wq = s_w[Q];
        amb = ((unsigned long long)F2 <= (unsigned long long)F1 + wq);
    }

    // compact ambiguous global query ids: one atomicAdd per wave + ballot rank
    {
        unsigned long long bal = __ballot(amb);
        int npop = __popcll(bal);
        unsigned base = 0;
        if (lane == 0 && npop) base = atomicAdd(ws_counter(wsf), (unsigned)npop);
        base = __shfl(base, 0, 64);
        if (amb) {
            int rank = __popcll(bal & ((1ULL << lane) - 1ULL));
            unsigned slot = base + (unsigned)rank;
            if (slot < CAP) ws_list(wsf)[slot] = q0 + Q;
        }
    }
    __syncthreads();

    // epilogue: wave w owns dims [8w, 8w+8); 256 queries via qh loop
    #pragma unroll
    for (int qh = 0; qh < 4; ++qh) {
        const int ql = qh * 64 + lane;
        const int jj = s_idx[ql];
        const int tt = t0 + ql;
        float* op = out + ((size_t)b * Dc + wave * 8) * Tc + tt;
        #pragma unroll
        for (int dd = 0; dd < 8; ++dd)
            op[(size_t)dd * Tc] = cb[(wave * 8 + dd) * Ec + jj];
        if (wave == 0) out[ZQ + q0 + ql] = (float)jj;
    }
}

// Kernel B: grid-stride the dense list, one wave per ambiguous query.
// Exact numpy-fp32 rescan (frozen recipe), overwrites z_q / z_id for that query.
__global__ __launch_bounds__(256) void vq_rescan(
    const float* __restrict__ z, const float* __restrict__ cbfull,
    const int* __restrict__ cbidx, _Float16* __restrict__ wsf,
    float* __restrict__ out) {
    const int lane = threadIdx.x & 63;
    const int wv = threadIdx.x >> 6;                       // 0..3
    const unsigned cnt0 = *ws_counter(wsf);
    const unsigned count = cnt0 < CAP ? cnt0 : CAP;
    const int gw = blockIdx.x * 4 + wv;                    // global wave id, 0..1023
    if ((unsigned)gw >= count) return;

    const int ci = cbidx[0] & 3;
    const float* __restrict__ cb = cbfull + (size_t)ci * (Dc * Ec);
    const float* __restrict__ c2g = (const float*)(wsf + 32768);
    const int* __restrict__ list = ws_list(wsf);

    for (unsigned e = gw; e < count; e += 1024) {
        const int qid = list[e];                           // wave-uniform
        const int b = qid >> 13, t = qid & (Tc - 1);
        const float* zq = z + (size_t)b * Dc * Tc + t;
        float zr[64];
        #pragma unroll
        for (int d = 0; d < 64; ++d) zr[d] = zq[(size_t)d * Tc];
        float rr[8];
        #pragma unroll
        for (int u = 0; u < 8; ++u) rr[u] = __fmul_rn(zr[u], zr[u]);
        #pragma unroll
        for (int i = 8; i < 64; i += 8)
            #pragma unroll
            for (int u = 0; u < 8; ++u)
                rr[u] = __fadd_rn(rr[u], __fmul_rn(zr[i + u], zr[i + u]));
        float s1 = __fadd_rn(__fadd_rn(__fadd_rn(rr[0], rr[1]), __fadd_rn(rr[2], rr[3])),
                             __fadd_rn(__fadd_rn(rr[4], rr[5]), __fadd_rn(rr[6], rr[7])));
        float bk = __int_as_float(0x7f800000);
        int bj = 0;
        for (int u = 0; u < 8; ++u) {
            int j = u * 64 + lane;
            float G = 0.f;
            #pragma unroll
            for (int d = 0; d < 64; ++d) G = __fmaf_rn(zr[d], cb[d * Ec + j], G);
            float key = __fadd_rn(__fsub_rn(s1, __fmul_rn(2.0f, G)), c2g[j]);
            if (key < bk) { bk = key; bj = j; }
        }
        #pragma unroll
        for (int m = 1; m < 64; m <<= 1) {
            float pk = __shfl_xor(bk, m, 64);
            int pj = __shfl_xor(bj, m, 64);
            if (pk < bk || (pk == bk && pj < bj)) { bk = pk; bj = pj; }
        }
        // overwrite outputs (bj uniform after reduce; lane d writes dim d)
        out[((size_t)b * Dc + lane) * Tc + t] = cb[lane * Ec + bj];
        if (lane == 0) out[ZQ + qid] = (float)bj;
    }
}

extern "C" void kernel_launch(void* const* d_in, const int* in_sizes, int n_in,
                              void* d_out, int out_size, void* d_ws, size_t ws_size,
                              hipStream_t stream) {
    const float* z = (const float*)d_in[0];
    const float* cbfull = (const float*)d_in[1];
    const int* cbidx = (const int*)d_in[2];
    _Float16* wsf = (_Float16*)d_ws;
    float* out = (float*)d_out;

    hipLaunchKernelGGL(vq_prep, dim3(16), dim3(256), 0, stream, cbfull, cbidx, wsf);
    hipLaunchKernelGGL(vq_main, dim3(NBLK), dim3(512), 0, stream, z, cbfull, cbidx, wsf, out);
    hipLaunchKernelGGL(vq_rescan, dim3(256), dim3(256), 0, stream, z, cbfull, cbidx, wsf, out);
}

// Round 12
// 151.465 us; speedup vs baseline: 2.6785x; 2.6785x over previous
//
#include <hip/hip_runtime.h>

// VQ layer B=16,D=64,T=8192,E=512 — f16 MFMA prefilter + exact numpy-fp32 windowed refine.
// Frozen exact recipe (r2..r11, absmax 0): s1=pairwise-8; G=seq-k FMA; c2=seq outer;
// key=(s1-2G)+c2 left-assoc; first-index strict-min.
// Round 12: rescan rebuilt. r11's B had 1 wave/SIMD + zr[64] spill (VGPR=48) -> 416us.
// Now: z -> LDS broadcast (no reg array), d-outer/u-inner (8 ILP chains, coalesced cb),
// 4096 grid-stride waves (~1.4 entries each). prep/main unchanged from r11.
// ws layout: [0,65536)B f16 frags; [65536,67584)B c2 float[512]; [67584]B u32 counter;
//            [67600,133136)B int list[16384].

constexpr int Dc = 64, Ec = 512, Tc = 8192;
constexpr int QTOT = 131072, ZQ = 8388608;
constexpr int QPB = 256;          // 8 waves x 32 queries
constexpr int NBLK = QTOT / QPB;  // 512
constexpr int CAP = 16384;        // list capacity (measured amb rate ~4.3% -> ~5600)

using half8  = __attribute__((ext_vector_type(8))) _Float16;
using f32x16 = __attribute__((ext_vector_type(16))) float;

__device__ __forceinline__ unsigned* ws_counter(_Float16* wsf) {
    return (unsigned*)((char*)wsf + 67584);
}
__device__ __forceinline__ int* ws_list(_Float16* wsf) {
    return (int*)((char*)wsf + 67600);
}

// prep: (a) 64 slots x 1KB f16 frags (r9-validated layout, c scaled x512),
//       (b) c2 numpy-exact (seq outer-axis), (c) zero the compaction counter.
__global__ void vq_prep(const float* __restrict__ cbfull, const int* __restrict__ cbidx,
                        _Float16* __restrict__ wsf) {
    int tid = blockIdx.x * 256 + threadIdx.x;
    if (tid == 0) *ws_counter(wsf) = 0;
    const float* cb = cbfull + (size_t)(cbidx[0] & 3) * (Dc * Ec);
    if (tid < 512) {
        float c = cb[tid];
        float a = __fmul_rn(c, c);
        for (int d = 1; d < Dc; ++d) { c = cb[d * Ec + tid]; a = __fadd_rn(a, __fmul_rn(c, c)); }
        ((float*)(wsf + 32768))[tid] = a;
    }
    if (tid >= 4096) return;
    int l = tid & 63, c = (tid >> 6) & 3, g = tid >> 8;
    int n = g * 32 + (l & 31);
    int kbase = c * 16 + (l >> 5) * 8;
    _Float16* dst = wsf + (size_t)(g * 4 + c) * 512 + l * 8;
    #pragma unroll
    for (int i = 0; i < 8; ++i)
        dst[i] = (_Float16)(cb[(kbase + i) * Ec + n] * 512.0f);
}

__global__ __launch_bounds__(512) void vq_main(
    const float* __restrict__ z, const float* __restrict__ cbfull,
    const int* __restrict__ cbidx, _Float16* __restrict__ wsf,
    float* __restrict__ out) {
    __shared__ __attribute__((aligned(16))) _Float16 s_frag[32768];  // 64KB
    __shared__ float s_c2[Ec];
    __shared__ unsigned s_w[QPB];
    __shared__ int s_idx[QPB];

    const int tid = threadIdx.x;
    const int lane = tid & 63;
    const int wave = __builtin_amdgcn_readfirstlane(tid >> 6);  // 0..7 (SGPR)
    const int col = lane & 31, hh = lane >> 5;
    const int q0 = blockIdx.x * QPB;
    const int b = q0 >> 13, t0 = q0 & (Tc - 1);
    const int myq = wave * 32 + col;
    const int t = t0 + myq;

    const int ci = cbidx[0] & 3;
    const float* __restrict__ cb = cbfull + (size_t)ci * (Dc * Ec);

    // query vector -> registers FIRST (HBM latency overlaps staging below)
    float zv[32];
    const float* zp = z + (size_t)b * Dc * Tc + t;
    #pragma unroll
    for (int c = 0; c < 4; ++c)
        #pragma unroll
        for (int i = 0; i < 8; ++i)
            zv[c * 8 + i] = zp[(size_t)(c * 16 + hh * 8 + i) * Tc];

    // one-shot stage: 64KB frags, 8 uint4/thread, coalesced, static indices
    {
        const uint4* src = (const uint4*)wsf;
        uint4* dst = (uint4*)s_frag;
        #pragma unroll
        for (int k = 0; k < 8; ++k) dst[tid + k * 512] = src[tid + k * 512];
    }
    if (tid < 512) s_c2[tid] = ((const float*)(wsf + 32768))[tid];

    // ambiguity window (r9-validated constants)
    float s1p = 0.f;
    #pragma unroll
    for (int e = 0; e < 32; ++e) s1p = __fmaf_rn(zv[e], zv[e], s1p);
    float s1b = (s1p + __shfl_xor(s1p, 32, 64)) * 1.001f + 0.01f;
    float wf = 2.5e-7f * (s1b + 1.f) + 3.2e-5f * sqrtf(s1b) + 1e-5f;
    unsigned w_int = (s1b > 880.f) ? 0x7FFFFFFFu : (unsigned)(wf * 2.147483648e9f) + 512u;
    if (hh == 0) s_w[myq] = w_int;

    // A-frags: u' = -16*z, f16 hi + lo
    half8 uhf[4], ulf[4];
    #pragma unroll
    for (int c = 0; c < 4; ++c)
        #pragma unroll
        for (int i = 0; i < 8; ++i) {
            float f = -16.0f * zv[c * 8 + i];
            _Float16 h = (_Float16)f;
            float hf = (float)h;
            uhf[c][i] = h;
            ulf[c][i] = (_Float16)(f - hf);
        }

    __syncthreads();   // frags + c2 + s_w ready

    // GEMM: 16 groups x {4 ds_read_b128, 8 MFMA f16, pack+min1/min2}; waves independent.
    // kb pre-biased: acc = 4096*(c2 - 2*z.c + 3) in [2^13,2^14) (s1<=880 guard).
    unsigned m1[16], m2[16];
    #pragma unroll
    for (int r = 0; r < 16; ++r) { m1[r] = 0xFFFFFFFFu; m2[r] = 0xFFFFFFFFu; }

    #pragma unroll 2
    for (int g = 0; g < 16; ++g) {
        const float kb = __fmaf_rn(s_c2[g * 32 + col], 4096.0f, 12288.0f);
        f32x16 acc;
        #pragma unroll
        for (int r = 0; r < 16; ++r) acc[r] = kb;
        #pragma unroll
        for (int c = 0; c < 4; ++c) {
            half8 chf = *(const half8*)(s_frag + (size_t)(g * 4 + c) * 512 + lane * 8);
            acc = __builtin_amdgcn_mfma_f32_32x32x16_f16(uhf[c], chf, acc, 0, 0, 0);
            acc = __builtin_amdgcn_mfma_f32_32x32x16_f16(ulf[c], chf, acc, 0, 0, 0);
        }
        const unsigned jj = (unsigned)(g * 32 + col);
        #pragma unroll
        for (int r = 0; r < 16; ++r) {
            unsigned key = (__float_as_uint(acc[r]) << 9) | jj;   // exp fixed -> monotone
            unsigned mx = key > m1[r] ? key : m1[r];
            m1[r] = key < m1[r] ? key : m1[r];
            m2[r] = mx < m2[r] ? mx : m2[r];
        }
    }

    // min1/min2 butterfly across 32 code-cols (register-only)
    #pragma unroll
    for (int st = 1; st < 32; st <<= 1) {
        #pragma unroll
        for (int r = 0; r < 16; ++r) {
            unsigned o1 = __shfl_xor(m1[r], st, 64);
            unsigned o2 = __shfl_xor(m2[r], st, 64);
            unsigned mx = m1[r] > o1 ? m1[r] : o1;
            m1[r] = m1[r] < o1 ? m1[r] : o1;
            m2[r] = m2[r] < o2 ? m2[r] : o2;
            m2[r] = m2[r] < mx ? m2[r] : mx;
        }
    }

    // lane col<16 owns accumulator r=col
    unsigned F1 = 0xFFFFFFFFu, F2 = 0xFFFFFFFFu;
    #pragma unroll
    for (int r = 0; r < 16; ++r) if (col == r) { F1 = m1[r]; F2 = m2[r]; }
    bool amb = false;
    int Q = 0;
    if (col < 16) {
        int row = (col & 3) + 8 * (col >> 2) + 4 * hh;   // verified 32x32 C/D row map
        Q = wave * 32 + row;
        s_idx[Q] = (int)(F1 & 511u);
        unsigned wq = s_w[Q];
        amb = ((unsigned long long)F2 <= (unsigned long long)F1 + wq);
    }

    // compact ambiguous global query ids: one atomicAdd per wave + ballot rank
    {
        unsigned long long bal = __ballot(amb);
        int npop = __popcll(bal);
        unsigned base = 0;
        if (lane == 0 && npop) base = atomicAdd(ws_counter(wsf), (unsigned)npop);
        base = __shfl(base, 0, 64);
        if (amb) {
            int rank = __popcll(bal & ((1ULL << lane) - 1ULL));
            unsigned slot = base + (unsigned)rank;
            if (slot < CAP) ws_list(wsf)[slot] = q0 + Q;
        }
    }
    __syncthreads();

    // epilogue: wave w owns dims [8w, 8w+8); 256 queries via qh loop
    #pragma unroll
    for (int qh = 0; qh < 4; ++qh) {
        const int ql = qh * 64 + lane;
        const int jj = s_idx[ql];
        const int tt = t0 + ql;
        float* op = out + ((size_t)b * Dc + wave * 8) * Tc + tt;
        #pragma unroll
        for (int dd = 0; dd < 8; ++dd)
            op[(size_t)dd * Tc] = cb[(wave * 8 + dd) * Ec + jj];
        if (wave == 0) out[ZQ + q0 + ql] = (float)jj;
    }
}

// Kernel B: grid-stride, one wave per ambiguous query. z -> LDS broadcast (no reg
// array / no spill); d-outer u-inner = 8 independent numpy seq-k FMA chains per lane;
// cb + c2 loads coalesced. Exact numpy-fp32 recipe, overwrites z_q / z_id.
__global__ __launch_bounds__(256) void vq_rescan(
    const float* __restrict__ z, const float* __restrict__ cbfull,
    const int* __restrict__ cbidx, _Float16* __restrict__ wsf,
    float* __restrict__ out) {
    __shared__ float s_z[4][64];
    const int lane = threadIdx.x & 63;
    const int wv = threadIdx.x >> 6;                       // 0..3
    const unsigned cnt0 = *ws_counter(wsf);
    const unsigned count = cnt0 < CAP ? cnt0 : CAP;

    const int ci = cbidx[0] & 3;
    const float* __restrict__ cb = cbfull + (size_t)ci * (Dc * Ec);
    const float* __restrict__ c2g = (const float*)(wsf + 32768);
    const int* __restrict__ list = ws_list(wsf);

    for (unsigned e = blockIdx.x * 4 + wv; e < count; e += 4096) {
        const int qid = list[e];                           // wave-uniform
        const int b = qid >> 13, t = qid & (Tc - 1);
        // lane d gathers z[b,d,t] -> LDS (one instruction, 64 lines in flight)
        s_z[wv][lane] = z[((size_t)b * Dc + lane) * Tc + t];
        // (same-wave LDS dep; compiler inserts lgkmcnt before first read)

        // s1: numpy pairwise-8, computed redundantly on all lanes from LDS broadcasts
        float rr[8];
        #pragma unroll
        for (int u = 0; u < 8; ++u) { float v = s_z[wv][u]; rr[u] = __fmul_rn(v, v); }
        #pragma unroll
        for (int i = 8; i < 64; i += 8)
            #pragma unroll
            for (int u = 0; u < 8; ++u) {
                float v = s_z[wv][i + u];
                rr[u] = __fadd_rn(rr[u], __fmul_rn(v, v));
            }
        const float s1 = __fadd_rn(
            __fadd_rn(__fadd_rn(rr[0], rr[1]), __fadd_rn(rr[2], rr[3])),
            __fadd_rn(__fadd_rn(rr[4], rr[5]), __fadd_rn(rr[6], rr[7])));

        // G: lane handles codes j = u*64+lane; numpy sgemm = seq-k FMA chain per code
        float acc[8];
        #pragma unroll
        for (int u = 0; u < 8; ++u) acc[u] = 0.0f;
        #pragma unroll 4
        for (int d = 0; d < 64; ++d) {
            const float zd = s_z[wv][d];
            #pragma unroll
            for (int u = 0; u < 8; ++u)
                acc[u] = __fmaf_rn(zd, cb[d * Ec + u * 64 + lane], acc[u]);
        }
        float bk = __int_as_float(0x7f800000);
        int bj = 0;
        #pragma unroll
        for (int u = 0; u < 8; ++u) {
            int j = u * 64 + lane;
            float key = __fadd_rn(__fsub_rn(s1, __fmul_rn(2.0f, acc[u])), c2g[j]);
            if (key < bk) { bk = key; bj = j; }   // j ascending -> first-index
        }
        #pragma unroll
        for (int m = 1; m < 64; m <<= 1) {
            float pk = __shfl_xor(bk, m, 64);
            int pj = __shfl_xor(bj, m, 64);
            if (pk < bk || (pk == bk && pj < bj)) { bk = pk; bj = pj; }
        }
        // overwrite outputs (bj uniform after reduce; lane d writes dim d)
        out[((size_t)b * Dc + lane) * Tc + t] = cb[lane * Ec + bj];
        if (lane == 0) out[ZQ + qid] = (float)bj;
    }
}

extern "C" void kernel_launch(void* const* d_in, const int* in_sizes, int n_in,
                              void* d_out, int out_size, void* d_ws, size_t ws_size,
                              hipStream_t stream) {
    const float* z = (const float*)d_in[0];
    const float* cbfull = (const float*)d_in[1];
    const int* cbidx = (const int*)d_in[2];
    _Float16* wsf = (_Float16*)d_ws;
    float* out = (float*)d_out;

    hipLaunchKernelGGL(vq_prep, dim3(16), dim3(256), 0, stream, cbfull, cbidx, wsf);
    hipLaunchKernelGGL(vq_main, dim3(NBLK), dim3(512), 0, stream, z, cbfull, cbidx, wsf, out);
    hipLaunchKernelGGL(vq_rescan, dim3(1024), dim3(256), 0, stream, z, cbfull, cbidx, wsf, out);
}